// Round 1
// 91237.994 us; speedup vs baseline: 1.0979x; 1.0979x over previous
//
#include <hip/hip_runtime.h>

// ---------- types & helpers ----------
typedef __bf16 bf16x8 __attribute__((ext_vector_type(8)));
typedef float  f32x4  __attribute__((ext_vector_type(4)));

__device__ __forceinline__ float bf2f(unsigned short u) {
  union { unsigned int i; float f; } v; v.i = ((unsigned int)u) << 16; return v.f;
}
__device__ __forceinline__ unsigned short f2bf(float f) {
  union { float f; unsigned int u; } v; v.f = f;
  unsigned int r = v.u + 0x7fffu + ((v.u >> 16) & 1u);
  return (unsigned short)(r >> 16);
}
__device__ __forceinline__ float sigm(float x)   { return 1.f / (1.f + __expf(-x)); }
__device__ __forceinline__ float tanh_f(float x) { return 2.f / (1.f + __expf(-2.f * x)) - 1.f; }
__device__ __forceinline__ bf16x8 ld8(const unsigned short* p) {
  return *reinterpret_cast<const bf16x8*>(p);
}

// ---------- fp32 -> bf16 bulk convert (weights & x), once per launch ----------
__global__ __launch_bounds__(256) void f32_to_bf16(const float* __restrict__ src,
                                                   unsigned short* __restrict__ dst, int n4) {
  int i = blockIdx.x * blockDim.x + threadIdx.x;
  const int stride = gridDim.x * blockDim.x;
  const float4* s4 = (const float4*)src;
  ushort4* d4 = (ushort4*)dst;
  for (; i < n4; i += stride) {
    float4 v = s4[i];
    ushort4 o;
    o.x = f2bf(v.x); o.y = f2bf(v.y); o.z = f2bf(v.z); o.w = f2bf(v.w);
    d4[i] = o;
  }
}

// accumulate one quarter (kq) of a K-segment into 4 gate accumulators.
// C = total K/32 chunks of this segment (compile-time), divisible by 4.
template<int C>
__device__ __forceinline__ void seg_quarter(f32x4 acc[4],
    const unsigned short* __restrict__ a, int astride,
    const unsigned short* __restrict__ w, int wstride,
    int m0, int j0, int quad, int col, int kq)
{
  constexpr int CQ = C / 4;
  const unsigned short* ar = a + (size_t)(m0 + col) * astride + quad * 8 + kq * CQ * 32;
  const unsigned short* wr = w + quad * 8 + kq * CQ * 32;
#pragma unroll
  for (int c = 0; c < CQ; c++) {
    bf16x8 af = ld8(ar + c * 32);
#pragma unroll
    for (int g = 0; g < 4; g++) {
      acc[g] = __builtin_amdgcn_mfma_f32_16x16x32_bf16(
          af, ld8(wr + (size_t)(g * 128 + j0 + col) * wstride + c * 32),
          acc[g], 0, 0, 0);
    }
  }
}

// ---------- K1/K3: standard LSTM cell (adapt cells), hidden=128, gates=512 ----------
// grid: 8 blocks x 1024 thr. block -> 16 hidden cols; wave = (m_tile, k_quarter).
// K split 4-ways across waves, LDS reduction, k_quarter==0 waves run the epilogue.
template<int C0, int C1, int C2, int C3>
__global__ __launch_bounds__(1024) void adapt_cell(
    const unsigned short* __restrict__ a0, int as0, const unsigned short* __restrict__ w0, int ws0,
    const unsigned short* __restrict__ a1, int as1, const unsigned short* __restrict__ w1, int ws1,
    const unsigned short* __restrict__ a2, int as2, const unsigned short* __restrict__ w2, int ws2,
    const unsigned short* __restrict__ a3, int as3, const unsigned short* __restrict__ w3, int ws3,
    const float* __restrict__ bih, const float* __restrict__ bhh,
    float* __restrict__ cbuf, unsigned short* __restrict__ hbuf)
{
  const int tid = threadIdx.x;
  const int wave = tid >> 6, lane = tid & 63;
  const int mwave = wave >> 2, kq = wave & 3;
  const int quad = lane >> 4, col = lane & 15;
  const int m0 = mwave * 16, j0 = blockIdx.x * 16;

  f32x4 acc[4] = {};
  seg_quarter<C0>(acc, a0, as0, w0, ws0, m0, j0, quad, col, kq);
  seg_quarter<C1>(acc, a1, as1, w1, ws1, m0, j0, quad, col, kq);
  seg_quarter<C2>(acc, a2, as2, w2, ws2, m0, j0, quad, col, kq);
  seg_quarter<C3>(acc, a3, as3, w3, ws3, m0, j0, quad, col, kq);

  // [kq-1][mwave][gate][lane] : lane-contiguous f32x4 -> conflict-free b128
  __shared__ f32x4 red[3][4][4][64];
  if (kq) {
#pragma unroll
    for (int g = 0; g < 4; g++) red[kq - 1][mwave][g][lane] = acc[g];
  }
  __syncthreads();
  if (kq) return;

#pragma unroll
  for (int p = 0; p < 3; p++)
#pragma unroll
    for (int g = 0; g < 4; g++) acc[g] += red[p][mwave][g][lane];

  const int j = j0 + col;
  const float b0 = bih[j]       + bhh[j];
  const float b1 = bih[128 + j] + bhh[128 + j];
  const float b2 = bih[256 + j] + bhh[256 + j];
  const float b3 = bih[384 + j] + bhh[384 + j];
#pragma unroll
  for (int r = 0; r < 4; r++) {
    const int m = m0 + quad * 4 + r;
    const float i_ = sigm(acc[0][r] + b0);
    const float f_ = sigm(acc[1][r] + b1);
    const float g_ = tanh_f(acc[2][r] + b2);
    const float o_ = sigm(acc[3][r] + b3);
    const int idx = m * 128 + j;
    const float c2 = f_ * cbuf[idx] + i_ * g_;
    cbuf[idx] = c2;
    hbuf[idx] = f2bf(o_ * tanh_f(c2));
  }
}

// ---------- K2a/K4a: x-hat / h-hat production only (ahe gate slices now fused into alstm) ----------
// grid: (xn+hn)/64 blocks x 256 thr. block -> 64 n cols, wave -> 16 batch rows.
__global__ __launch_bounds__(256) void policy_scale(
    const unsigned short* __restrict__ A,    // 64 x 128 bf16 (adapt hx, current step)
    const unsigned short* __restrict__ pw,   // policy weights, rows [0, xn+hn) used here
    const float* __restrict__ pb,
    const unsigned short* __restrict__ xsrc, int xn,
    const unsigned short* __restrict__ hsrc, int hn,
    unsigned short* __restrict__ xhat, unsigned short* __restrict__ hhat)
{
  const int wave = threadIdx.x >> 6, lane = threadIdx.x & 63;
  const int quad = lane >> 4, col = lane & 15;
  const int m0 = wave * 16, n0 = blockIdx.x * 64;

  f32x4 acc[4] = {};
  const unsigned short* arow = A + (size_t)(m0 + col) * 128 + quad * 8;
#pragma unroll
  for (int c = 0; c < 4; c++) {
    bf16x8 af = ld8(arow + c * 32);
#pragma unroll
    for (int s = 0; s < 4; s++) {
      acc[s] = __builtin_amdgcn_mfma_f32_16x16x32_bf16(
          af, ld8(pw + (size_t)(n0 + s * 16 + col) * 128 + quad * 8 + c * 32),
          acc[s], 0, 0, 0);
    }
  }
#pragma unroll
  for (int s = 0; s < 4; s++) {
    const int n = n0 + s * 16 + col;
    const float bias = pb[n];
#pragma unroll
    for (int r = 0; r < 4; r++) {
      const int m = m0 + quad * 4 + r;
      const float v = acc[s][r] + bias;
      if (n < xn) {
        xhat[m * xn + n] = f2bf(v * bf2f(xsrc[m * xn + n]));
      } else {
        hhat[m * hn + (n - xn)] = f2bf(v * bf2f(hsrc[m * hn + (n - xn)]));
      }
    }
  }
}

// ---------- K2b/K4b: adaptive LSTM cell (f cells), hidden=1024, gates=4096 ----------
// grid: 64 blocks x 512 thr. block -> 16 hidden cols; wave = (m_tile, k_half).
// K split 2-ways across waves + LDS reduce. Policy gate-scale slices (12 x 16 cols of
// ahe, K=128) computed in-register by the k_half==0 waves -> ahe never materialized.
template<int XK, int HK>
__global__ __launch_bounds__(512) void alstm_cell(
    const unsigned short* __restrict__ xhat,  // 64 x XK bf16
    const unsigned short* __restrict__ hhat,  // 64 x HK bf16
    const unsigned short* __restrict__ wih,   // 4096 x XK bf16
    const unsigned short* __restrict__ whh,   // 4096 x HK bf16
    const float* __restrict__ fb,             // 4096 fp32
    const unsigned short* __restrict__ ax,    // 64 x 128 bf16 (adapt hx, current step)
    const unsigned short* __restrict__ pw,    // policy weights (full)
    const float* __restrict__ pb,             // policy bias (full)
    int ig_off, int hg_off, int ab_off,       // row offsets into pw/pb
    float* __restrict__ cbuf, unsigned short* __restrict__ hbuf, float* __restrict__ outp)
{
  const int tid = threadIdx.x;
  const int wave = tid >> 6, lane = tid & 63;
  const int mwave = wave >> 1, kh = wave & 1;
  const int quad = lane >> 4, col = lane & 15;
  const int m0 = mwave * 16, j0 = blockIdx.x * 16;

  constexpr int XC = XK / 32, HC = HK / 32;

  // policy slices first on kh==0 so their loads overlap the main GEMM
  f32x4 pg0[4] = {}, pg1[4] = {}, pg2[4] = {};
  if (kh == 0) {
    const unsigned short* ar = ax + (size_t)(m0 + col) * 128 + quad * 8;
#pragma unroll
    for (int c = 0; c < 4; c++) {
      bf16x8 af = ld8(ar + c * 32);
#pragma unroll
      for (int g = 0; g < 4; g++) {
        pg0[g] = __builtin_amdgcn_mfma_f32_16x16x32_bf16(
            af, ld8(pw + (size_t)(ig_off + g * 1024 + j0 + col) * 128 + quad * 8 + c * 32), pg0[g], 0, 0, 0);
        pg1[g] = __builtin_amdgcn_mfma_f32_16x16x32_bf16(
            af, ld8(pw + (size_t)(hg_off + g * 1024 + j0 + col) * 128 + quad * 8 + c * 32), pg1[g], 0, 0, 0);
        pg2[g] = __builtin_amdgcn_mfma_f32_16x16x32_bf16(
            af, ld8(pw + (size_t)(ab_off + g * 1024 + j0 + col) * 128 + quad * 8 + c * 32), pg2[g], 0, 0, 0);
      }
    }
  }

  f32x4 ig[4] = {}, hg[4] = {};
  {
    const unsigned short* ar = xhat + (size_t)(m0 + col) * XK + quad * 8 + kh * (XC / 2) * 32;
    const unsigned short* wr = wih + quad * 8 + kh * (XC / 2) * 32;
#pragma unroll
    for (int c = 0; c < XC / 2; c++) {
      bf16x8 af = ld8(ar + c * 32);
#pragma unroll
      for (int g = 0; g < 4; g++) {
        ig[g] = __builtin_amdgcn_mfma_f32_16x16x32_bf16(
            af, ld8(wr + (size_t)(g * 1024 + j0 + col) * XK + c * 32), ig[g], 0, 0, 0);
      }
    }
  }
  {
    const unsigned short* ar = hhat + (size_t)(m0 + col) * HK + quad * 8 + kh * (HC / 2) * 32;
    const unsigned short* wr = whh + quad * 8 + kh * (HC / 2) * 32;
#pragma unroll
    for (int c = 0; c < HC / 2; c++) {
      bf16x8 af = ld8(ar + c * 32);
#pragma unroll
      for (int g = 0; g < 4; g++) {
        hg[g] = __builtin_amdgcn_mfma_f32_16x16x32_bf16(
            af, ld8(wr + (size_t)(g * 1024 + j0 + col) * HK + c * 32), hg[g], 0, 0, 0);
      }
    }
  }

  // [mwave][acc][lane] : lane-contiguous f32x4 -> conflict-free b128
  __shared__ f32x4 red[4][8][64];
  if (kh == 1) {
#pragma unroll
    for (int g = 0; g < 4; g++) { red[mwave][g][lane] = ig[g]; red[mwave][4 + g][lane] = hg[g]; }
  }
  __syncthreads();
  if (kh == 1) return;

#pragma unroll
  for (int g = 0; g < 4; g++) { ig[g] += red[mwave][g][lane]; hg[g] += red[mwave][4 + g][lane]; }

  const int j = j0 + col;
  float pb0[4], pb1[4], pb2[4], fbv[4];
#pragma unroll
  for (int g = 0; g < 4; g++) {
    pb0[g] = pb[ig_off + g * 1024 + j];
    pb1[g] = pb[hg_off + g * 1024 + j];
    pb2[g] = pb[ab_off + g * 1024 + j];
    fbv[g] = fb[g * 1024 + j];
  }
#pragma unroll
  for (int r = 0; r < 4; r++) {
    const int m = m0 + quad * 4 + r;
    float gate[4];
#pragma unroll
    for (int g = 0; g < 4; g++) {
      gate[g] = ig[g][r] * (pg0[g][r] + pb0[g])
              + hg[g][r] * (pg1[g][r] + pb1[g])
              + fbv[g]   * (pg2[g][r] + pb2[g]);
    }
    const float i_ = sigm(gate[0]);
    const float f_ = sigm(gate[1]);
    const float g_ = tanh_f(gate[2]);
    const float o_ = sigm(gate[3]);
    const int idx = m * 1024 + j;
    const float c2 = f_ * cbuf[idx] + i_ * g_;
    cbuf[idx] = c2;
    const float h = o_ * tanh_f(c2);
    hbuf[idx] = f2bf(h);
    if (outp) outp[idx] = h;
  }
}

extern "C" void kernel_launch(void* const* d_in, const int* in_sizes, int n_in,
                              void* d_out, int out_size, void* d_ws, size_t ws_size,
                              hipStream_t stream)
{
  const float* x      = (const float*)d_in[0];
  const float* a_wih0 = (const float*)d_in[1];
  const float* a_whh0 = (const float*)d_in[2];
  const float* a_bih0 = (const float*)d_in[3];
  const float* a_bhh0 = (const float*)d_in[4];
  const float* p_w0   = (const float*)d_in[5];
  const float* p_b0   = (const float*)d_in[6];
  const float* f_wih0 = (const float*)d_in[7];
  const float* f_whh0 = (const float*)d_in[8];
  const float* f_b0   = (const float*)d_in[9];
  const float* a_wih1 = (const float*)d_in[10];
  const float* a_whh1 = (const float*)d_in[11];
  const float* a_bih1 = (const float*)d_in[12];
  const float* a_bhh1 = (const float*)d_in[13];
  const float* p_w1   = (const float*)d_in[14];
  const float* p_b1   = (const float*)d_in[15];
  const float* f_wih1 = (const float*)d_in[16];
  const float* f_whh1 = (const float*)d_in[17];
  const float* f_b1   = (const float*)d_in[18];
  float* out = (float*)d_out;

  // ---- workspace carve-up (256B-aligned cursor) ----
  char* p = (char*)d_ws;
  auto alloc = [&](size_t bytes) { char* r = p; p += (bytes + 255) & ~(size_t)255; return r; };

  // recurrent state (zeroed each launch)
  float* a0c = (float*)alloc(64 * 128 * 4);
  float* a1c = (float*)alloc(64 * 128 * 4);
  float* f0c = (float*)alloc(64 * 1024 * 4);
  float* f1c = (float*)alloc(64 * 1024 * 4);
  unsigned short* a0xA = (unsigned short*)alloc(64 * 128 * 2);
  unsigned short* a0xB = (unsigned short*)alloc(64 * 128 * 2);
  unsigned short* a1xA = (unsigned short*)alloc(64 * 128 * 2);
  unsigned short* a1xB = (unsigned short*)alloc(64 * 128 * 2);
  unsigned short* f0x  = (unsigned short*)alloc(64 * 1024 * 2);
  unsigned short* f1x  = (unsigned short*)alloc(64 * 1024 * 2);
  const size_t zero_bytes = (size_t)(p - (char*)d_ws);

  // per-step scratch (fully written before read each step)
  unsigned short* xh0 = (unsigned short*)alloc(64 * 256 * 2);
  unsigned short* hh0 = (unsigned short*)alloc(64 * 1024 * 2);
  unsigned short* xh1 = (unsigned short*)alloc(64 * 1024 * 2);
  unsigned short* hh1 = (unsigned short*)alloc(64 * 1024 * 2);

  // bf16 conversions of x + weights
  unsigned short* xb      = (unsigned short*)alloc((size_t)8388608 * 2);
  unsigned short* a_wih0b = (unsigned short*)alloc((size_t)720896 * 2);
  unsigned short* a_whh0b = (unsigned short*)alloc((size_t)65536 * 2);
  unsigned short* p_w0b   = (unsigned short*)alloc((size_t)1736704 * 2);
  unsigned short* f_wih0b = (unsigned short*)alloc((size_t)1048576 * 2);
  unsigned short* f_whh0b = (unsigned short*)alloc((size_t)4194304 * 2);
  unsigned short* a_wih1b = (unsigned short*)alloc((size_t)1114112 * 2);
  unsigned short* a_whh1b = (unsigned short*)alloc((size_t)65536 * 2);
  unsigned short* p_w1b   = (unsigned short*)alloc((size_t)1835008 * 2);
  unsigned short* f_wih1b = (unsigned short*)alloc((size_t)4194304 * 2);
  unsigned short* f_whh1b = (unsigned short*)alloc((size_t)4194304 * 2);

  hipMemsetAsync(d_ws, 0, zero_bytes, stream);

  auto conv = [&](const float* s, unsigned short* d, size_t n) {
    int n4 = (int)(n >> 2);
    int blocks = (n4 + 255) / 256; if (blocks > 1024) blocks = 1024;
    f32_to_bf16<<<blocks, 256, 0, stream>>>(s, d, n4);
  };
  conv(x,      xb,      8388608);
  conv(a_wih0, a_wih0b, 720896);
  conv(a_whh0, a_whh0b, 65536);
  conv(p_w0,   p_w0b,   1736704);
  conv(f_wih0, f_wih0b, 1048576);
  conv(f_whh0, f_whh0b, 4194304);
  conv(a_wih1, a_wih1b, 1114112);
  conv(a_whh1, a_whh1b, 65536);
  conv(p_w1,   p_w1b,   1835008);
  conv(f_wih1, f_wih1b, 4194304);
  conv(f_whh1, f_whh1b, 4194304);

  for (int t = 0; t < 512; t++) {
    const unsigned short* xt = xb + (size_t)t * 64 * 256;
    unsigned short* a0x_cur  = (t & 1) ? a0xB : a0xA;
    unsigned short* a0x_prev = (t & 1) ? a0xA : a0xB;
    unsigned short* a1x_cur  = (t & 1) ? a1xB : a1xA;
    unsigned short* a1x_prev = (t & 1) ? a1xA : a1xB;

    // K1: adapt cell 0.  ax0 = [xt, f0x(prev), a1x(prev)], h = a0x(prev)
    adapt_cell<8, 32, 4, 4><<<8, 1024, 0, stream>>>(
        xt,       256,  a_wih0b,        1408,
        f0x,      1024, a_wih0b + 256,  1408,
        a1x_prev, 128,  a_wih0b + 1280, 1408,
        a0x_prev, 128,  a_whh0b,        128,
        a_bih0, a_bhh0, a0c, a0x_cur);

    // K2a: xh0 = xt*a_x ; hh0 = f0x(prev)*a_h   (N = 256+1024 = 1280)
    policy_scale<<<20, 256, 0, stream>>>(a0x_cur, p_w0b, p_b0,
                                         xt, 256, f0x, 1024, xh0, hh0);

    // K2b: f-cell 0 -> f0x, f0c  (policy gate-scales fused in-register)
    alstm_cell<256, 1024><<<64, 512, 0, stream>>>(xh0, hh0, f_wih0b, f_whh0b, f_b0,
                                                  a0x_cur, p_w0b, p_b0, 1280, 5376, 9472,
                                                  f0c, f0x, (float*)nullptr);

    // K3: adapt cell 1.  ax1 = [f0x(new), f1x(prev), a0x(new)], h = a1x(prev)
    adapt_cell<32, 32, 4, 4><<<8, 1024, 0, stream>>>(
        f0x,      1024, a_wih1b,        2176,
        f1x,      1024, a_wih1b + 1024, 2176,
        a0x_cur,  128,  a_wih1b + 2048, 2176,
        a1x_prev, 128,  a_whh1b,        128,
        a_bih1, a_bhh1, a1c, a1x_cur);

    // K4a: xh1 = f0x(new)*a_x ; hh1 = f1x(prev)*a_h   (N = 1024+1024 = 2048)
    policy_scale<<<32, 256, 0, stream>>>(a1x_cur, p_w1b, p_b1,
                                         f0x, 1024, f1x, 1024, xh1, hh1);

    // K4b: f-cell 1 -> f1x, f1c, and the step output (fp32)
    alstm_cell<1024, 1024><<<64, 512, 0, stream>>>(xh1, hh1, f_wih1b, f_whh1b, f_b1,
                                                   a1x_cur, p_w1b, p_b1, 2048, 6144, 10240,
                                                   f1c, f1x, out + (size_t)t * 64 * 1024);
  }
}